// Round 3
// baseline (568.984 us; speedup 1.0000x reference)
//
#include <hip/hip_runtime.h>

typedef __attribute__((ext_vector_type(8))) short short8;
typedef __attribute__((ext_vector_type(8))) unsigned short ushort8;
typedef __attribute__((ext_vector_type(4))) float f32x4;

#define DEV __device__ __forceinline__

DEV unsigned short f2bf(float f) {
  unsigned int u = __float_as_uint(f);
  u += 0x7fffu + ((u >> 16) & 1u);
  return (unsigned short)(u >> 16);
}
DEV float sigm(float x) { return 1.f / (1.f + __expf(-x)); }
DEV float tanh_(float x) { return 1.f - 2.f / (1.f + __expf(2.f * x)); }

typedef __attribute__((address_space(1))) const void* as1cv;
typedef __attribute__((address_space(3))) void* as3v;
DEV void gll16(const void* g, void* l) {
  __builtin_amdgcn_global_load_lds((as1cv)g, (as3v)l, 16, 0, 0);
}

// ---------------- sort (stable desc argsort of lengths) + gathers ---------------
__global__ void __launch_bounds__(256) k_sort(const float* __restrict__ x,
    const int* __restrict__ ptar, const int* __restrict__ tlen,
    int* __restrict__ sidx, int* __restrict__ lens, int* __restrict__ tok,
    float* __restrict__ xs, float* __restrict__ tail, int* __restrict__ bar) {
  __shared__ int ss[64];
  int tid = threadIdx.x;
  if (tid < 32) bar[tid] = 0;  // grid-barrier counters for k_steps
  if (tid < 64) {
    int li = tlen[tid];
    int rank = 0;
    for (int j = 0; j < 64; ++j) {
      int lj = tlen[j];
      rank += (lj > li || (lj == li && j < tid)) ? 1 : 0;
    }
    ss[rank] = tid;
  }
  __syncthreads();
  if (tid < 64) {
    int src = ss[tid];
    sidx[tid] = src;
    lens[tid] = tlen[src] - 1;
    tail[tid] = (float)src;
  }
  __syncthreads();
  for (int idx = tid; idx < 32 * 64; idx += 256) {
    int t = idx >> 6, b = idx & 63;
    tok[idx] = ptar[ss[b] * 33 + t];
  }
  for (int idx = tid; idx < 64 * 512; idx += 256) {
    int b = idx >> 9;
    xs[idx] = x[ss[b] * 512 + (idx & 511)];
  }
}

// -------- fused f32->bf16 conversions: Wpro(3072x512) | Wihb2 | Whb | xsb -------
__global__ void __launch_bounds__(256) k_convmany(
    const float* __restrict__ W_h0, const float* __restrict__ W_c0,
    const float* __restrict__ W_ih, const float* __restrict__ W_hh,
    const float* __restrict__ xs,
    unsigned short* __restrict__ Wpro, unsigned short* __restrict__ Wihb2,
    unsigned short* __restrict__ Whb, unsigned short* __restrict__ xsb) {
  long long g = (long long)(blockIdx.x * 256 + threadIdx.x) * 8;
  const float* src;
  unsigned short* dst;
  if (g < 262144) {
    src = W_h0 + g; dst = Wpro + g;
  } else if (g < 524288) {
    long long l = g - 262144; src = W_c0 + l; dst = Wpro + 262144 + l;
  } else if (g < 1572864) {
    long long l = g - 524288;
    long long r = l >> 9, c = l & 511;
    src = W_ih + r * 768 + c; dst = Wpro + 524288 + l;
  } else if (g < 2097152) {
    long long l = g - 1572864;
    long long r = l >> 8, c = l & 255;
    src = W_ih + r * 768 + 512 + c; dst = Wihb2 + l;
  } else if (g < 3145728) {
    long long l = g - 2097152; src = W_hh + l; dst = Whb + l;
  } else {
    long long l = g - 3145728; src = xs + l; dst = xsb + l;
  }
  float4 v0 = *(const float4*)src, v1 = *(const float4*)(src + 4);
  ushort8 o;
  o[0] = f2bf(v0.x); o[1] = f2bf(v0.y); o[2] = f2bf(v0.z); o[3] = f2bf(v0.w);
  o[4] = f2bf(v1.x); o[5] = f2bf(v1.y); o[6] = f2bf(v1.z); o[7] = f2bf(v1.w);
  *(ushort8*)dst = o;
}

// ---- prologue GEMM: [64x512]x[512x3072] -> h0 (bf16), c0 (f32), gx (f32) -------
__global__ void __launch_bounds__(256) k_pro(const unsigned short* __restrict__ xsb,
    const unsigned short* __restrict__ Wpro, const float* __restrict__ b_h0,
    const float* __restrict__ b_c0, const float* __restrict__ b_ih,
    const float* __restrict__ b_hh, unsigned short* __restrict__ h0b,
    float* __restrict__ c, float* __restrict__ gx) {
  int tid = threadIdx.x, lane = tid & 63, w = tid >> 6;
  int n0 = blockIdx.x * 64 + w * 16;
  int lr = lane & 15, lk = lane >> 4;
  f32x4 acc[4];
#pragma unroll
  for (int i = 0; i < 4; ++i) acc[i] = (f32x4){0.f, 0.f, 0.f, 0.f};
  const unsigned short* B = Wpro + (size_t)(n0 + lr) * 512 + lk * 8;
  const unsigned short* A = xsb + (size_t)lr * 512 + lk * 8;
#pragma unroll
  for (int ks = 0; ks < 16; ++ks) {
    short8 bfr = *(const short8*)(B + ks * 32);
#pragma unroll
    for (int mi = 0; mi < 4; ++mi) {
      short8 af = *(const short8*)(A + mi * 16 * 512 + ks * 32);
      acc[mi] = __builtin_amdgcn_mfma_f32_16x16x32_bf16(af, bfr, acc[mi], 0, 0, 0);
    }
  }
  int n = n0 + lr;
#pragma unroll
  for (int mi = 0; mi < 4; ++mi)
#pragma unroll
    for (int r = 0; r < 4; ++r) {
      int b = mi * 16 + lk * 4 + r;
      float v = acc[mi][r];
      if (n < 512) {
        h0b[b * 512 + n] = f2bf(v + b_h0[n]);
      } else if (n < 1024) {
        int u = n - 512;
        c[b * 512 + u] = v + b_c0[u];
      } else {
        int j = n - 1024;
        gx[(size_t)b * 2048 + j] = v + b_ih[j] + b_hh[j];
      }
    }
}

// ---------------- embedding gather -> bf16 Eb[2048][256] ------------------------
__global__ void __launch_bounds__(256) k_emb(const int* __restrict__ tok,
    const float* __restrict__ embed, unsigned short* __restrict__ Eb) {
  int gid = blockIdx.x * 256 + threadIdx.x;
  int row = gid >> 5, c8 = (gid & 31) * 8;
  const float* src = embed + (size_t)tok[row] * 256 + c8;
  float4 v0 = *(const float4*)src, v1 = *(const float4*)(src + 4);
  ushort8 o;
  o[0] = f2bf(v0.x); o[1] = f2bf(v0.y); o[2] = f2bf(v0.z); o[3] = f2bf(v0.w);
  o[4] = f2bf(v1.x); o[5] = f2bf(v1.y); o[6] = f2bf(v1.z); o[7] = f2bf(v1.w);
  *(ushort8*)(Eb + (size_t)row * 256 + c8) = o;
}

// ---- GA[m][j] = Eb[m] . Wihb2[j] + gx[m&63][j]   (2048x2048, K=256) ------------
__global__ void __launch_bounds__(256) k_ga2(const unsigned short* __restrict__ Eb,
    const unsigned short* __restrict__ Wb2, const float* __restrict__ gx,
    float* __restrict__ GA) {
  __shared__ alignas(16) char ldsbuf[32768];
  char* ldsA = ldsbuf;
  char* ldsB = ldsbuf + 16384;
  int bid = blockIdx.x;
  int mt = bid & 15, nt = bid >> 4;
  int m0 = mt * 128, n0 = nt * 128;
  int tid = threadIdx.x, lane = tid & 63, w = tid >> 6;
  int wm = w >> 1, wn = w & 1;
  f32x4 acc[4][4];
#pragma unroll
  for (int a = 0; a < 4; ++a)
#pragma unroll
    for (int bq = 0; bq < 4; ++bq) acc[a][bq] = (f32x4){0.f, 0.f, 0.f, 0.f};
  const unsigned short* Arow = Eb + (size_t)m0 * 256;
  const unsigned short* Brow = Wb2 + (size_t)n0 * 256;
  for (int kt = 0; kt < 4; ++kt) {
    int k0 = kt * 64;
    if (kt) __syncthreads();
#pragma unroll
    for (int j = 0; j < 4; ++j) {
      int ci = j * 256 + w * 64 + lane;
      int r = ci >> 3;
      int clog = ((ci & 7) << 4) ^ ((r & 7) << 4);
      int ldst = (j * 256 + w * 64) * 16;
      gll16((const char*)(Arow + (size_t)r * 256 + k0) + clog, ldsA + ldst);
      gll16((const char*)(Brow + (size_t)r * 256 + k0) + clog, ldsB + ldst);
    }
    __syncthreads();
#pragma unroll
    for (int kk = 0; kk < 2; ++kk) {
      short8 af[4], bf[4];
      int cb = kk * 64 + (lane >> 4) * 16;
#pragma unroll
      for (int i = 0; i < 4; ++i) {
        int ar = wm * 64 + i * 16 + (lane & 15);
        af[i] = *(const short8*)(ldsA + ar * 128 + (cb ^ ((ar & 7) << 4)));
        int br = wn * 64 + i * 16 + (lane & 15);
        bf[i] = *(const short8*)(ldsB + br * 128 + (cb ^ ((br & 7) << 4)));
      }
#pragma unroll
      for (int mi = 0; mi < 4; ++mi)
#pragma unroll
        for (int ni = 0; ni < 4; ++ni)
          acc[mi][ni] = __builtin_amdgcn_mfma_f32_16x16x32_bf16(
              af[mi], bf[ni], acc[mi][ni], 0, 0, 0);
    }
  }
#pragma unroll
  for (int mi = 0; mi < 4; ++mi) {
    int mb = m0 + wm * 64 + mi * 16 + ((lane >> 4) << 2);
#pragma unroll
    for (int r = 0; r < 4; ++r) {
      int m = mb + r;
#pragma unroll
      for (int ni = 0; ni < 4; ++ni) {
        int j = n0 + wn * 64 + ni * 16 + (lane & 15);
        GA[(size_t)m * 2048 + j] = acc[mi][ni][r] + gx[(size_t)(m & 63) * 2048 + j];
      }
    }
  }
}

// ---------------- ALL 32 LSTM steps in one persistent kernel --------------------
// blocks 0..63: steppers (mh = bid&1 picks 32 batch rows, ug = bid>>1 picks 16
// units). B (W_hh slice) in VGPRs for all steps; c in 2 regs/thread; h ping-pongs
// through global (LLC-resident, no LDS staging). Grid barrier per step.
// blocks 64..255: convert W_out f32->bf16 concurrently (hidden under steps).
__global__ void __launch_bounds__(256) k_steps(
    unsigned short* __restrict__ h0, unsigned short* __restrict__ h1,
    const float* __restrict__ c0, const float* __restrict__ GA,
    const unsigned short* __restrict__ Whb, const int* __restrict__ lens,
    unsigned short* __restrict__ Hm, int* __restrict__ bar,
    const float* __restrict__ W_out, unsigned short* __restrict__ Wob) {
  int tid = threadIdx.x, bid = blockIdx.x;
  if (bid >= 64) {
    for (long long i = ((long long)(bid - 64) * 256 + tid) * 8; i < 16384000LL;
         i += 192LL * 256 * 8) {
      float4 v0 = *(const float4*)(W_out + i);
      float4 v1 = *(const float4*)(W_out + i + 4);
      ushort8 o;
      o[0] = f2bf(v0.x); o[1] = f2bf(v0.y); o[2] = f2bf(v0.z); o[3] = f2bf(v0.w);
      o[4] = f2bf(v1.x); o[5] = f2bf(v1.y); o[6] = f2bf(v1.z); o[7] = f2bf(v1.w);
      *(ushort8*)(Wob + i) = o;
    }
    return;
  }
  __shared__ float Gs[4][32][16];
  int lane = tid & 63, g = tid >> 6, lr = lane & 15, lk = lane >> 4;
  int mh = bid & 1, u0 = (bid >> 1) * 16;

  short8 Bf[16];  // W_hh fragment: gate g, units u0..u0+16, all K — 64 VGPRs
  {
    const unsigned short* Bp = Whb + (size_t)(g * 512 + u0 + lr) * 512 + lk * 8;
#pragma unroll
    for (int ks = 0; ks < 16; ++ks) Bf[ks] = *(const short8*)(Bp + ks * 32);
  }
  int row0 = tid >> 4, uc = tid & 15;
  int b0 = mh * 32 + row0, b1 = b0 + 16;
  int u = u0 + uc;
  float cr0 = c0[b0 * 512 + u], cr1 = c0[b1 * 512 + u];
  int len0 = lens[b0], len1 = lens[b1];

  for (int t = 0; t < 32; ++t) {
    const unsigned short* hin = (t & 1) ? h1 : h0;
    unsigned short* hout = (t & 1) ? h0 : h1;
    const float* gab = GA + ((size_t)t * 64 + mh * 32) * 2048 + g * 512 + u0 + lr;
    float gv0[4], gv1[4];
#pragma unroll
    for (int r = 0; r < 4; ++r) {
      gv0[r] = gab[(size_t)(lk * 4 + r) * 2048];
      gv1[r] = gab[(size_t)(16 + lk * 4 + r) * 2048];
    }
    const unsigned short* Ap = hin + (size_t)(mh * 32 + lr) * 512 + lk * 8;
    f32x4 ac0 = {0.f, 0.f, 0.f, 0.f}, ac1 = {0.f, 0.f, 0.f, 0.f};
#pragma unroll
    for (int ks = 0; ks < 16; ++ks) {
      short8 a0 = *(const short8*)(Ap + ks * 32);
      short8 a1 = *(const short8*)(Ap + 8192 + ks * 32);
      ac0 = __builtin_amdgcn_mfma_f32_16x16x32_bf16(a0, Bf[ks], ac0, 0, 0, 0);
      ac1 = __builtin_amdgcn_mfma_f32_16x16x32_bf16(a1, Bf[ks], ac1, 0, 0, 0);
    }
#pragma unroll
    for (int r = 0; r < 4; ++r) {
      Gs[g][lk * 4 + r][lr] = ac0[r] + gv0[r];
      Gs[g][16 + lk * 4 + r][lr] = ac1[r] + gv1[r];
    }
    __syncthreads();
    {
      float fi = Gs[0][row0][uc], ff = Gs[1][row0][uc];
      float fg = Gs[2][row0][uc], fo = Gs[3][row0][uc];
      float cn = sigm(ff) * cr0 + sigm(fi) * tanh_(fg);
      float hn = sigm(fo) * tanh_(cn);
      bool act = len0 > t;
      cr0 = act ? cn : cr0;
      unsigned short hbv = f2bf(hn);
      unsigned short holdv = hin[b0 * 512 + u];
      hout[b0 * 512 + u] = act ? hbv : holdv;
      if (act) Hm[((size_t)b0 * 32 + t) * 512 + u] = hbv;
    }
    {
      float fi = Gs[0][row0 + 16][uc], ff = Gs[1][row0 + 16][uc];
      float fg = Gs[2][row0 + 16][uc], fo = Gs[3][row0 + 16][uc];
      float cn = sigm(ff) * cr1 + sigm(fi) * tanh_(fg);
      float hn = sigm(fo) * tanh_(cn);
      bool act = len1 > t;
      cr1 = act ? cn : cr1;
      unsigned short hbv = f2bf(hn);
      unsigned short holdv = hin[b1 * 512 + u];
      hout[b1 * 512 + u] = act ? hbv : holdv;
      if (act) Hm[((size_t)b1 * 32 + t) * 512 + u] = hbv;
    }
    __syncthreads();
    if (tid == 0) {
      __threadfence();
      __hip_atomic_fetch_add(&bar[t], 1, __ATOMIC_ACQ_REL,
                             __HIP_MEMORY_SCOPE_AGENT);
      while (__hip_atomic_load(&bar[t], __ATOMIC_ACQUIRE,
                               __HIP_MEMORY_SCOPE_AGENT) < 64)
        __builtin_amdgcn_s_sleep(1);
      __threadfence();
    }
    __syncthreads();
  }
}

// ------ pred[m'][n] = Hm[m'] . Wb[n] (+ b_out if active); m' = b*32+t -----------
__global__ void __launch_bounds__(256) k_gemm(const unsigned short* __restrict__ Hm,
    const unsigned short* __restrict__ Wb, const float* __restrict__ b_out,
    const int* __restrict__ lens, float* __restrict__ out) {
  __shared__ alignas(16) char ldsbuf[32768];
  char* ldsA = ldsbuf;
  char* ldsB = ldsbuf + 16384;
  int bid = blockIdx.x;
  int mt = bid & 15, nt = bid >> 4;  // nt-major: XCDs share one Wb slice
  int m0 = mt * 128, n0 = nt * 128;
  int tid = threadIdx.x, lane = tid & 63, w = tid >> 6;
  int wm = w >> 1, wn = w & 1;
  f32x4 acc[4][4];
#pragma unroll
  for (int a = 0; a < 4; ++a)
#pragma unroll
    for (int bq = 0; bq < 4; ++bq) acc[a][bq] = (f32x4){0.f, 0.f, 0.f, 0.f};
  const unsigned short* Arow = Hm + (size_t)m0 * 512;
  const unsigned short* Brow = Wb + (size_t)n0 * 512;
  for (int kt = 0; kt < 8; ++kt) {
    int k0 = kt * 64;
    if (kt) __syncthreads();
#pragma unroll
    for (int j = 0; j < 4; ++j) {
      int ci = j * 256 + w * 64 + lane;
      int r = ci >> 3;
      int clog = ((ci & 7) << 4) ^ ((r & 7) << 4);
      int ldst = (j * 256 + w * 64) * 16;
      gll16((const char*)(Arow + (size_t)r * 512 + k0) + clog, ldsA + ldst);
      gll16((const char*)(Brow + (size_t)r * 512 + k0) + clog, ldsB + ldst);
    }
    __syncthreads();
#pragma unroll
    for (int kk = 0; kk < 2; ++kk) {
      short8 af[4], bf[4];
      int cb = kk * 64 + (lane >> 4) * 16;
#pragma unroll
      for (int i = 0; i < 4; ++i) {
        int ar = wm * 64 + i * 16 + (lane & 15);
        af[i] = *(const short8*)(ldsA + ar * 128 + (cb ^ ((ar & 7) << 4)));
        int br = wn * 64 + i * 16 + (lane & 15);
        bf[i] = *(const short8*)(ldsB + br * 128 + (cb ^ ((br & 7) << 4)));
      }
#pragma unroll
      for (int mi = 0; mi < 4; ++mi)
#pragma unroll
        for (int ni = 0; ni < 4; ++ni)
          acc[mi][ni] = __builtin_amdgcn_mfma_f32_16x16x32_bf16(
              af[mi], bf[ni], acc[mi][ni], 0, 0, 0);
    }
  }
#pragma unroll
  for (int mi = 0; mi < 4; ++mi) {
    int mb = m0 + wm * 64 + mi * 16 + ((lane >> 4) << 2);
#pragma unroll
    for (int r = 0; r < 4; ++r) {
      int m = mb + r;
      int b = m >> 5, t = m & 31;
      bool act = lens[b] > t;
      size_t orow = (size_t)m * 32000;
#pragma unroll
      for (int ni = 0; ni < 4; ++ni) {
        int n = n0 + wn * 64 + ni * 16 + (lane & 15);
        out[orow + n] = act ? (acc[mi][ni][r] + b_out[n]) : 0.f;
      }
    }
  }
}

extern "C" void kernel_launch(void* const* d_in, const int* in_sizes, int n_in,
                              void* d_out, int out_size, void* d_ws, size_t ws_size,
                              hipStream_t stream) {
  const float* x     = (const float*)d_in[0];
  const int*   ptar  = (const int*)d_in[1];
  const int*   tlen  = (const int*)d_in[2];
  const float* embed = (const float*)d_in[3];
  const float* W_h0  = (const float*)d_in[4];
  const float* b_h0  = (const float*)d_in[5];
  const float* W_c0  = (const float*)d_in[6];
  const float* b_c0  = (const float*)d_in[7];
  const float* W_ih  = (const float*)d_in[8];
  const float* W_hh  = (const float*)d_in[9];
  const float* b_ih  = (const float*)d_in[10];
  const float* b_hh  = (const float*)d_in[11];
  const float* W_out = (const float*)d_in[12];
  const float* b_out = (const float*)d_in[13];
  float* out = (float*)d_out;

  char* ws = (char*)d_ws;
  size_t off = 0;
  auto alloc = [&](size_t bytes) {
    void* p = ws + off;
    off += (bytes + 255) & ~(size_t)255;
    return p;
  };
  unsigned short* Wob = (unsigned short*)alloc(32000ull * 512 * 2);
  unsigned short* Hm  = (unsigned short*)alloc(2048ull * 512 * 2);
  float* xs   = (float*)alloc(64 * 512 * 4);
  unsigned short* h0b = (unsigned short*)alloc(64 * 512 * 2);
  unsigned short* h1b = (unsigned short*)alloc(64 * 512 * 2);
  float* cbuf = (float*)alloc(64 * 512 * 4);
  float* gx   = (float*)alloc(64 * 2048 * 4);
  int* sidx = (int*)alloc(64 * 4);
  int* lens = (int*)alloc(64 * 4);
  int* tok  = (int*)alloc(2048 * 4);
  int* bar  = (int*)alloc(32 * 4);

  // scratch in d_out's prediction region (all consumed before k_gemm overwrites)
  float* GA = out;                                             // 2048*2048 f32
  unsigned short* Wpro  = (unsigned short*)(out + 4194304);    // 3072*512 bf16
  unsigned short* Wihb2 = (unsigned short*)(out + 4980736);    // 2048*256 bf16
  unsigned short* Whb   = (unsigned short*)(out + 5242880);    // 2048*512 bf16
  unsigned short* Eb    = (unsigned short*)(out + 5767168);    // 2048*256 bf16
  unsigned short* xsb   = (unsigned short*)(out + 6029312);    // 64*512 bf16
  float* tail = out + 65536000;                                // sorted_indices

  k_sort<<<1, 256, 0, stream>>>(x, ptar, tlen, sidx, lens, tok, xs, tail, bar);
  k_convmany<<<1552, 256, 0, stream>>>(W_h0, W_c0, W_ih, W_hh, xs,
                                       Wpro, Wihb2, Whb, xsb);
  k_pro<<<48, 256, 0, stream>>>(xsb, Wpro, b_h0, b_c0, b_ih, b_hh, h0b, cbuf, gx);
  k_emb<<<256, 256, 0, stream>>>(tok, embed, Eb);
  k_ga2<<<256, 256, 0, stream>>>(Eb, Wihb2, gx, GA);

  k_steps<<<256, 256, 0, stream>>>(h0b, h1b, cbuf, GA, Whb, lens, Hm, bar,
                                   W_out, Wob);

  k_gemm<<<4000, 256, 0, stream>>>(Hm, Wob, b_out, lens, out);
  (void)in_sizes; (void)n_in; (void)out_size; (void)ws_size;
}

// Round 4
// 362.378 us; speedup vs baseline: 1.5701x; 1.5701x over previous
//
#include <hip/hip_runtime.h>

typedef __attribute__((ext_vector_type(8))) short short8;
typedef __attribute__((ext_vector_type(8))) unsigned short ushort8;
typedef __attribute__((ext_vector_type(4))) float f32x4;

#define DEV __device__ __forceinline__

DEV unsigned short f2bf(float f) {
  unsigned int u = __float_as_uint(f);
  u += 0x7fffu + ((u >> 16) & 1u);
  return (unsigned short)(u >> 16);
}
DEV float sigm(float x) { return 1.f / (1.f + __expf(-x)); }
DEV float tanh_(float x) { return 1.f - 2.f / (1.f + __expf(2.f * x)); }

typedef __attribute__((address_space(1))) const void* as1cv;
typedef __attribute__((address_space(3))) void* as3v;
DEV void gll16(const void* g, void* l) {
  __builtin_amdgcn_global_load_lds((as1cv)g, (as3v)l, 16, 0, 0);
}

// ------- sort (stable desc argsort) + gathers + packing metadata ----------------
__global__ void __launch_bounds__(256) k_sort(const float* __restrict__ x,
    const int* __restrict__ ptar, const int* __restrict__ tlen,
    int* __restrict__ sidx, int* __restrict__ lens, int* __restrict__ base,
    int* __restrict__ inv, int* __restrict__ Pw, int* __restrict__ tok,
    float* __restrict__ xs, float* __restrict__ tail) {
  __shared__ int ss[64], ls[64], bs[64];
  int tid = threadIdx.x;
  if (tid < 64) {
    int li = tlen[tid];
    int rank = 0;
    for (int j = 0; j < 64; ++j) {
      int lj = tlen[j];
      rank += (lj > li || (lj == li && j < tid)) ? 1 : 0;
    }
    ss[rank] = tid;
  }
  __syncthreads();
  if (tid < 64) {
    int src = ss[tid];
    sidx[tid] = src;
    int l = tlen[src] - 1;
    ls[tid] = l;
    lens[tid] = l;
    tail[tid] = (float)src;
  }
  __syncthreads();
  if (tid == 0) {
    int s = 0;
    for (int b = 0; b < 64; ++b) { bs[b] = s; base[b] = s; s += ls[b]; }
    Pw[0] = s;
  }
  __syncthreads();
  for (int idx = tid; idx < 2048; idx += 256) {
    int b = idx >> 5, t = idx & 31;
    if (t < ls[b]) inv[bs[b] + t] = idx;
  }
  for (int idx = tid; idx < 32 * 64; idx += 256) {
    int t = idx >> 6, b = idx & 63;
    tok[idx] = ptar[ss[b] * 33 + t];
  }
  for (int idx = tid; idx < 64 * 512; idx += 256) {
    int b = idx >> 9;
    xs[idx] = x[ss[b] * 512 + (idx & 511)];
  }
}

// -------- fused f32->bf16 conversions: Wpro(3072x512) | Wihb2 | Whb | xsb -------
__global__ void __launch_bounds__(256) k_convmany(
    const float* __restrict__ W_h0, const float* __restrict__ W_c0,
    const float* __restrict__ W_ih, const float* __restrict__ W_hh,
    const float* __restrict__ xs,
    unsigned short* __restrict__ Wpro, unsigned short* __restrict__ Wihb2,
    unsigned short* __restrict__ Whb, unsigned short* __restrict__ xsb) {
  long long g = (long long)(blockIdx.x * 256 + threadIdx.x) * 8;
  const float* src;
  unsigned short* dst;
  if (g < 262144) {
    src = W_h0 + g; dst = Wpro + g;
  } else if (g < 524288) {
    long long l = g - 262144; src = W_c0 + l; dst = Wpro + 262144 + l;
  } else if (g < 1572864) {
    long long l = g - 524288;
    long long r = l >> 9, c = l & 511;
    src = W_ih + r * 768 + c; dst = Wpro + 524288 + l;
  } else if (g < 2097152) {
    long long l = g - 1572864;
    long long r = l >> 8, c = l & 255;
    src = W_ih + r * 768 + 512 + c; dst = Wihb2 + l;
  } else if (g < 3145728) {
    long long l = g - 2097152; src = W_hh + l; dst = Whb + l;
  } else {
    long long l = g - 3145728; src = xs + l; dst = xsb + l;
  }
  float4 v0 = *(const float4*)src, v1 = *(const float4*)(src + 4);
  ushort8 o;
  o[0] = f2bf(v0.x); o[1] = f2bf(v0.y); o[2] = f2bf(v0.z); o[3] = f2bf(v0.w);
  o[4] = f2bf(v1.x); o[5] = f2bf(v1.y); o[6] = f2bf(v1.z); o[7] = f2bf(v1.w);
  *(ushort8*)dst = o;
}

// ---- prologue GEMM: [64x512]x[512x3072] -> h0 (bf16), c0 (f32), gx (f32) -------
__global__ void __launch_bounds__(256) k_pro(const unsigned short* __restrict__ xsb,
    const unsigned short* __restrict__ Wpro, const float* __restrict__ b_h0,
    const float* __restrict__ b_c0, const float* __restrict__ b_ih,
    const float* __restrict__ b_hh, unsigned short* __restrict__ h0b,
    float* __restrict__ c, float* __restrict__ gx) {
  int tid = threadIdx.x, lane = tid & 63, w = tid >> 6;
  int n0 = blockIdx.x * 64 + w * 16;
  int lr = lane & 15, lk = lane >> 4;
  f32x4 acc[4];
#pragma unroll
  for (int i = 0; i < 4; ++i) acc[i] = (f32x4){0.f, 0.f, 0.f, 0.f};
  const unsigned short* B = Wpro + (size_t)(n0 + lr) * 512 + lk * 8;
  const unsigned short* A = xsb + (size_t)lr * 512 + lk * 8;
#pragma unroll
  for (int ks = 0; ks < 16; ++ks) {
    short8 bfr = *(const short8*)(B + ks * 32);
#pragma unroll
    for (int mi = 0; mi < 4; ++mi) {
      short8 af = *(const short8*)(A + mi * 16 * 512 + ks * 32);
      acc[mi] = __builtin_amdgcn_mfma_f32_16x16x32_bf16(af, bfr, acc[mi], 0, 0, 0);
    }
  }
  int n = n0 + lr;
#pragma unroll
  for (int mi = 0; mi < 4; ++mi)
#pragma unroll
    for (int r = 0; r < 4; ++r) {
      int b = mi * 16 + lk * 4 + r;
      float v = acc[mi][r];
      if (n < 512) {
        h0b[b * 512 + n] = f2bf(v + b_h0[n]);
      } else if (n < 1024) {
        int u = n - 512;
        c[b * 512 + u] = v + b_c0[u];
      } else {
        int j = n - 1024;
        gx[(size_t)b * 2048 + j] = v + b_ih[j] + b_hh[j];
      }
    }
}

// ---------------- embedding gather -> bf16 Eb[2048][256] ------------------------
__global__ void __launch_bounds__(256) k_emb(const int* __restrict__ tok,
    const float* __restrict__ embed, unsigned short* __restrict__ Eb) {
  int gid = blockIdx.x * 256 + threadIdx.x;
  int row = gid >> 5, c8 = (gid & 31) * 8;
  const float* src = embed + (size_t)tok[row] * 256 + c8;
  float4 v0 = *(const float4*)src, v1 = *(const float4*)(src + 4);
  ushort8 o;
  o[0] = f2bf(v0.x); o[1] = f2bf(v0.y); o[2] = f2bf(v0.z); o[3] = f2bf(v0.w);
  o[4] = f2bf(v1.x); o[5] = f2bf(v1.y); o[6] = f2bf(v1.z); o[7] = f2bf(v1.w);
  *(ushort8*)(Eb + (size_t)row * 256 + c8) = o;
}

// ---- GA = Eb @ Wihb2^T + gx (blocks 0..255); blocks 256..505: W_out->bf16 ------
__global__ void __launch_bounds__(256) k_ga2(const unsigned short* __restrict__ Eb,
    const unsigned short* __restrict__ Wb2, const float* __restrict__ gx,
    float* __restrict__ GA, const float* __restrict__ W_out,
    unsigned short* __restrict__ Wob) {
  int bid = blockIdx.x;
  int tid = threadIdx.x;
  if (bid >= 256) {  // W_out f32->bf16, hidden alongside GA compute
    long long basei = (long long)(bid - 256) * 65536;
#pragma unroll 4
    for (int it = 0; it < 32; ++it) {
      long long i = basei + (long long)it * 2048 + tid * 8;
      float4 v0 = *(const float4*)(W_out + i);
      float4 v1 = *(const float4*)(W_out + i + 4);
      ushort8 o;
      o[0] = f2bf(v0.x); o[1] = f2bf(v0.y); o[2] = f2bf(v0.z); o[3] = f2bf(v0.w);
      o[4] = f2bf(v1.x); o[5] = f2bf(v1.y); o[6] = f2bf(v1.z); o[7] = f2bf(v1.w);
      *(ushort8*)(Wob + i) = o;
    }
    return;
  }
  __shared__ alignas(16) char ldsbuf[32768];
  char* ldsA = ldsbuf;
  char* ldsB = ldsbuf + 16384;
  int mt = bid & 15, nt = bid >> 4;
  int m0 = mt * 128, n0 = nt * 128;
  int lane = tid & 63, w = tid >> 6;
  int wm = w >> 1, wn = w & 1;
  f32x4 acc[4][4];
#pragma unroll
  for (int a = 0; a < 4; ++a)
#pragma unroll
    for (int bq = 0; bq < 4; ++bq) acc[a][bq] = (f32x4){0.f, 0.f, 0.f, 0.f};
  const unsigned short* Arow = Eb + (size_t)m0 * 256;
  const unsigned short* Brow = Wb2 + (size_t)n0 * 256;
  for (int kt = 0; kt < 4; ++kt) {
    int k0 = kt * 64;
    if (kt) __syncthreads();
#pragma unroll
    for (int j = 0; j < 4; ++j) {
      int ci = j * 256 + w * 64 + lane;
      int r = ci >> 3;
      int clog = ((ci & 7) << 4) ^ ((r & 7) << 4);
      int ldst = (j * 256 + w * 64) * 16;
      gll16((const char*)(Arow + (size_t)r * 256 + k0) + clog, ldsA + ldst);
      gll16((const char*)(Brow + (size_t)r * 256 + k0) + clog, ldsB + ldst);
    }
    __syncthreads();
#pragma unroll
    for (int kk = 0; kk < 2; ++kk) {
      short8 af[4], bf[4];
      int cb = kk * 64 + (lane >> 4) * 16;
#pragma unroll
      for (int i = 0; i < 4; ++i) {
        int ar = wm * 64 + i * 16 + (lane & 15);
        af[i] = *(const short8*)(ldsA + ar * 128 + (cb ^ ((ar & 7) << 4)));
        int br = wn * 64 + i * 16 + (lane & 15);
        bf[i] = *(const short8*)(ldsB + br * 128 + (cb ^ ((br & 7) << 4)));
      }
#pragma unroll
      for (int mi = 0; mi < 4; ++mi)
#pragma unroll
        for (int ni = 0; ni < 4; ++ni)
          acc[mi][ni] = __builtin_amdgcn_mfma_f32_16x16x32_bf16(
              af[mi], bf[ni], acc[mi][ni], 0, 0, 0);
    }
  }
#pragma unroll
  for (int mi = 0; mi < 4; ++mi) {
    int mb = m0 + wm * 64 + mi * 16 + ((lane >> 4) << 2);
#pragma unroll
    for (int r = 0; r < 4; ++r) {
      int m = mb + r;
#pragma unroll
      for (int ni = 0; ni < 4; ++ni) {
        int j = n0 + wn * 64 + ni * 16 + (lane & 15);
        GA[(size_t)m * 2048 + j] = acc[mi][ni][r] + gx[(size_t)(m & 63) * 2048 + j];
      }
    }
  }
}

// ---------------- one LSTM step, 128 blocks -------------------------------------
// block = (mq 0..3: 16 batch rows) x (ug 0..31: 16 units); wave = gate.
__global__ void __launch_bounds__(256) k_step3(
    const unsigned short* __restrict__ hin, unsigned short* __restrict__ hout,
    float* __restrict__ c, const float* __restrict__ GA,
    const unsigned short* __restrict__ Whb, const int* __restrict__ lens,
    const int* __restrict__ base, unsigned short* __restrict__ Hm, int t) {
  __shared__ float Gs[4][16][16];
  int tid = threadIdx.x, lane = tid & 63, g = tid >> 6;
  int lr = lane & 15, lk = lane >> 4;
  int mq = blockIdx.x & 3, ug = blockIdx.x >> 2;
  int r0 = mq * 16, u0 = ug * 16;

  // gate pre-adds (issue early, overlap with MFMA loads)
  const float* gab = GA + ((size_t)t * 64 + r0) * 2048 + g * 512 + u0 + lr;
  float gv[4];
#pragma unroll
  for (int r = 0; r < 4; ++r) gv[r] = gab[(size_t)(lk * 4 + r) * 2048];

  const unsigned short* Bp = Whb + (size_t)(g * 512 + u0 + lr) * 512 + lk * 8;
  const unsigned short* Ap = hin + (size_t)(r0 + lr) * 512 + lk * 8;
  f32x4 acc = (f32x4){0.f, 0.f, 0.f, 0.f};
#pragma unroll
  for (int ks = 0; ks < 16; ++ks) {
    short8 a0 = *(const short8*)(Ap + ks * 32);
    short8 b0 = *(const short8*)(Bp + ks * 32);
    acc = __builtin_amdgcn_mfma_f32_16x16x32_bf16(a0, b0, acc, 0, 0, 0);
  }
#pragma unroll
  for (int r = 0; r < 4; ++r) Gs[g][lk * 4 + r][lr] = acc[r] + gv[r];
  __syncthreads();

  int row = tid >> 4, uc = tid & 15;
  int b = r0 + row, u = u0 + uc;
  float fi = Gs[0][row][uc], ff = Gs[1][row][uc];
  float fg = Gs[2][row][uc], fo = Gs[3][row][uc];
  float cold = c[b * 512 + u];
  float cn = sigm(ff) * cold + sigm(fi) * tanh_(fg);
  float hn = sigm(fo) * tanh_(cn);
  bool act = lens[b] > t;
  if (act) c[b * 512 + u] = cn;
  unsigned short hbv = f2bf(hn);
  hout[b * 512 + u] = act ? hbv : hin[b * 512 + u];
  if (act) Hm[((size_t)(base[b] + t)) * 512 + u] = hbv;
}

// ---------------- zero-fill inactive output rows --------------------------------
__global__ void __launch_bounds__(256) k_zf(const int* __restrict__ lens,
    float* __restrict__ out) {
  int m = blockIdx.x;
  int b = m >> 5, t = m & 31;
  if (lens[b] > t) return;
  float4 z = {0.f, 0.f, 0.f, 0.f};
  float* row = out + (size_t)m * 32000;
  for (int i = threadIdx.x * 4; i < 32000; i += 1024)
    *(float4*)(row + i) = z;
}

// ------ packed GEMM: pred[p][n] = Hm[p].Wob[n] + b_out[n]; scatter via inv ------
__global__ void __launch_bounds__(512) k_gemm(const unsigned short* __restrict__ Hm,
    const unsigned short* __restrict__ Wb, const float* __restrict__ b_out,
    const int* __restrict__ inv, const int* __restrict__ Pw,
    float* __restrict__ out) {
  __shared__ alignas(16) char ldsbuf[49152];  // A 16KB | B 32KB
  char* ldsA = ldsbuf;
  char* ldsB = ldsbuf + 16384;
  int P = Pw[0];
  int sb = (blockIdx.x & 7) * 250 + (blockIdx.x >> 3);  // XCD chunks, 2000%8==0
  int mt = sb % 16, nt = sb / 16;                        // nt-major within chunk
  int m0 = mt * 128, n0 = nt * 256;
  if (m0 >= P) return;  // fully-inactive m-tile
  int tid = threadIdx.x, lane = tid & 63, w = tid >> 6;
  int wm = w >> 2, wn = w & 3;  // 2x4 waves, 64x64 tiles
  f32x4 acc[4][4];
#pragma unroll
  for (int a = 0; a < 4; ++a)
#pragma unroll
    for (int bq = 0; bq < 4; ++bq) acc[a][bq] = (f32x4){0.f, 0.f, 0.f, 0.f};
  const unsigned short* Arow = Hm + (size_t)m0 * 512;
  const unsigned short* Brow = Wb + (size_t)n0 * 512;
  for (int kt = 0; kt < 8; ++kt) {
    int k0 = kt * 64;
    if (kt) __syncthreads();
#pragma unroll
    for (int j = 0; j < 2; ++j) {  // A: 1024 chunks
      int ci = j * 512 + tid;
      int r = ci >> 3;
      int clog = ((ci & 7) << 4) ^ ((r & 7) << 4);
      gll16((const char*)(Arow + (size_t)r * 512 + k0) + clog, ldsA + ci * 16);
    }
#pragma unroll
    for (int j = 0; j < 4; ++j) {  // B: 2048 chunks
      int ci = j * 512 + tid;
      int r = ci >> 3;
      int clog = ((ci & 7) << 4) ^ ((r & 7) << 4);
      gll16((const char*)(Brow + (size_t)r * 512 + k0) + clog, ldsB + ci * 16);
    }
    __syncthreads();
#pragma unroll
    for (int kk = 0; kk < 2; ++kk) {
      short8 af[4], bf[4];
      int cb = kk * 64 + (lane >> 4) * 16;
#pragma unroll
      for (int i = 0; i < 4; ++i) {
        int ar = wm * 64 + i * 16 + (lane & 15);
        af[i] = *(const short8*)(ldsA + ar * 128 + (cb ^ ((ar & 7) << 4)));
        int br = wn * 64 + i * 16 + (lane & 15);
        bf[i] = *(const short8*)(ldsB + br * 128 + (cb ^ ((br & 7) << 4)));
      }
#pragma unroll
      for (int mi = 0; mi < 4; ++mi)
#pragma unroll
        for (int ni = 0; ni < 4; ++ni)
          acc[mi][ni] = __builtin_amdgcn_mfma_f32_16x16x32_bf16(
              af[mi], bf[ni], acc[mi][ni], 0, 0, 0);
    }
  }
#pragma unroll
  for (int mi = 0; mi < 4; ++mi) {
    int pb = m0 + wm * 64 + mi * 16 + ((lane >> 4) << 2);
#pragma unroll
    for (int r = 0; r < 4; ++r) {
      int p = pb + r;
      if (p >= P) continue;
      size_t orow = (size_t)inv[p] * 32000;
#pragma unroll
      for (int ni = 0; ni < 4; ++ni) {
        int n = n0 + wn * 64 + ni * 16 + (lane & 15);
        out[orow + n] = acc[mi][ni][r] + b_out[n];
      }
    }
  }
}

extern "C" void kernel_launch(void* const* d_in, const int* in_sizes, int n_in,
                              void* d_out, int out_size, void* d_ws, size_t ws_size,
                              hipStream_t stream) {
  const float* x     = (const float*)d_in[0];
  const int*   ptar  = (const int*)d_in[1];
  const int*   tlen  = (const int*)d_in[2];
  const float* embed = (const float*)d_in[3];
  const float* W_h0  = (const float*)d_in[4];
  const float* b_h0  = (const float*)d_in[5];
  const float* W_c0  = (const float*)d_in[6];
  const float* b_c0  = (const float*)d_in[7];
  const float* W_ih  = (const float*)d_in[8];
  const float* W_hh  = (const float*)d_in[9];
  const float* b_ih  = (const float*)d_in[10];
  const float* b_hh  = (const float*)d_in[11];
  const float* W_out = (const float*)d_in[12];
  const float* b_out = (const float*)d_in[13];
  float* out = (float*)d_out;

  char* ws = (char*)d_ws;
  size_t off = 0;
  auto alloc = [&](size_t bytes) {
    void* p = ws + off;
    off += (bytes + 255) & ~(size_t)255;
    return p;
  };
  unsigned short* Wob = (unsigned short*)alloc(32000ull * 512 * 2);
  unsigned short* Hm  = (unsigned short*)alloc(2048ull * 512 * 2);
  float* xs   = (float*)alloc(64 * 512 * 4);
  unsigned short* h0b = (unsigned short*)alloc(64 * 512 * 2);
  unsigned short* h1b = (unsigned short*)alloc(64 * 512 * 2);
  float* cbuf = (float*)alloc(64 * 512 * 4);
  float* gx   = (float*)alloc(64 * 2048 * 4);
  int* sidx = (int*)alloc(64 * 4);
  int* lens = (int*)alloc(64 * 4);
  int* base = (int*)alloc(64 * 4);
  int* inv  = (int*)alloc(2048 * 4);
  int* Pw   = (int*)alloc(4);
  int* tok  = (int*)alloc(2048 * 4);

  // scratch in d_out's prediction region (all consumed before zf/gemm overwrite)
  float* GA = out;                                             // 2048*2048 f32
  unsigned short* Wpro  = (unsigned short*)(out + 4194304);    // 3072*512 bf16
  unsigned short* Wihb2 = (unsigned short*)(out + 4980736);    // 2048*256 bf16
  unsigned short* Whb   = (unsigned short*)(out + 5242880);    // 2048*512 bf16
  unsigned short* Eb    = (unsigned short*)(out + 5767168);    // 2048*256 bf16
  unsigned short* xsb   = (unsigned short*)(out + 6029312);    // 64*512 bf16
  float* tail = out + 65536000;                                // sorted_indices

  k_sort<<<1, 256, 0, stream>>>(x, ptar, tlen, sidx, lens, base, inv, Pw, tok,
                                xs, tail);
  k_convmany<<<1552, 256, 0, stream>>>(W_h0, W_c0, W_ih, W_hh, xs,
                                       Wpro, Wihb2, Whb, xsb);
  k_pro<<<48, 256, 0, stream>>>(xsb, Wpro, b_h0, b_c0, b_ih, b_hh, h0b, cbuf, gx);
  k_emb<<<256, 256, 0, stream>>>(tok, embed, Eb);
  k_ga2<<<506, 256, 0, stream>>>(Eb, Wihb2, gx, GA, W_out, Wob);

  unsigned short* hb[2] = {h0b, h1b};
  for (int t = 0; t < 32; ++t)
    k_step3<<<128, 256, 0, stream>>>(hb[t & 1], hb[(t + 1) & 1], cbuf, GA, Whb,
                                     lens, base, Hm, t);

  k_zf<<<2048, 256, 0, stream>>>(lens, out);
  k_gemm<<<2000, 512, 0, stream>>>(Hm, Wob, b_out, inv, Pw, out);
  (void)in_sizes; (void)n_in; (void)out_size; (void)ws_size;
}